// Round 4
// baseline (108.020 us; speedup 1.0000x reference)
//
#include <hip/hip_runtime.h>
#include <math.h>

constexpr int NCAPS = 1152;
constexpr int CIN   = 8;
constexpr int COUT  = 16;
constexpr int BATCH = 128;
constexpr int DCAPS = 10;
constexpr int NTHREADS = 768;        // 12 waves
constexpr int NWAVES = NTHREADS / 64;
constexpr int JPT = 6;               // rows per thread per b (6*192 = 1152)

// Block = (d, batch-pair): each w row is loaded ONCE and used for two b's,
// halving L2 w-traffic vs R2/R3 (737 -> 369 MB). Lane = nsub*4 + oq keeps
// w-loads at 16 x 64B contiguous segments per instruction.
// launch_bounds(.,1): R2/R3 showed the allocator overshoots the min-waves
// target and SPILLS (WRITE_SIZE 13.5/28 MB of scratch); min=1 gives it a
// 256-VGPR cap so the ~120 live regs (2x24 u + 12 logits + transients) fit.
__global__ __launch_bounds__(NTHREADS, 1) void digitcaps_kernel(
    const float* __restrict__ x,    // [128, 1152, 8]
    const float* __restrict__ w,    // [10, 1152, 8, 16]
    float* __restrict__ out)        // [10, 128, 16]
{
    __shared__ float4 red[2][NWAVES][4];   // per-wave partial s, [b][wave][oq]
    __shared__ float  sbuf[2][NWAVES];     // softmax max partials
    __shared__ float  zbuf[2][NWAVES];     // softmax sum partials
    __shared__ float4 vsh[2][4];           // squashed v, [b][oq]

    // 640 blocks: i&7 = XCD. Each XCD works a fixed 16-b column through all
    // 10 d's; resident footprint per XCD ~ 4 w-slices + 576 KB x < 4 MB L2.
    const int i   = blockIdx.x;
    const int xcd = i & 7;
    const int k   = i >> 3;              // 0..79
    const int d   = k >> 3;              // 0..9
    const int bp  = xcd * 8 + (k & 7);   // 0..63
    const int b0  = 2 * bp;
    const int b1  = b0 + 1;

    const int t    = threadIdx.x;
    const int wave = t >> 6;
    const int lane = t & 63;
    const int nsub = lane >> 2;   // 0..15
    const int oq   = lane & 3;    // 0..3

    const float* xb0 = x + (size_t)b0 * NCAPS * CIN;
    const float* xb1 = x + (size_t)b1 * NCAPS * CIN;
    const float* wd  = w + (size_t)d * NCAPS * CIN * COUT + oq * 4;

    float4 u0[JPT], u1[JPT];
    #pragma unroll
    for (int j = 0; j < JPT; ++j) {
        const int n = j * 192 + wave * 16 + nsub;
        const float* wr = wd + (size_t)n * CIN * COUT;
        float4 W[CIN];
        #pragma unroll
        for (int ii = 0; ii < CIN; ++ii)
            W[ii] = *(const float4*)(wr + ii * COUT);
        const float4* xr0 = (const float4*)(xb0 + (size_t)n * CIN);
        const float4* xr1 = (const float4*)(xb1 + (size_t)n * CIN);
        float4 xa0 = xr0[0], xc0 = xr0[1];
        float4 xa1 = xr1[0], xc1 = xr1[1];
        float xs0[CIN] = {xa0.x, xa0.y, xa0.z, xa0.w, xc0.x, xc0.y, xc0.z, xc0.w};
        float xs1[CIN] = {xa1.x, xa1.y, xa1.z, xa1.w, xc1.x, xc1.y, xc1.z, xc1.w};
        float4 a0 = {0.f, 0.f, 0.f, 0.f};
        float4 a1 = {0.f, 0.f, 0.f, 0.f};
        #pragma unroll
        for (int ii = 0; ii < CIN; ++ii) {
            a0.x = fmaf(xs0[ii], W[ii].x, a0.x);
            a0.y = fmaf(xs0[ii], W[ii].y, a0.y);
            a0.z = fmaf(xs0[ii], W[ii].z, a0.z);
            a0.w = fmaf(xs0[ii], W[ii].w, a0.w);
            a1.x = fmaf(xs1[ii], W[ii].x, a1.x);
            a1.y = fmaf(xs1[ii], W[ii].y, a1.y);
            a1.z = fmaf(xs1[ii], W[ii].z, a1.z);
            a1.w = fmaf(xs1[ii], W[ii].w, a1.w);
        }
        u0[j] = a0;
        u1[j] = a1;
    }

    float bb0[JPT], bb1[JPT];
    #pragma unroll
    for (int j = 0; j < JPT; ++j) { bb0[j] = 0.f; bb1[j] = 0.f; }

    #pragma unroll
    for (int it = 0; it < 3; ++it) {
        float4 p0 = {0.f, 0.f, 0.f, 0.f};
        float4 p1 = {0.f, 0.f, 0.f, 0.f};
        float z0 = 0.f, z1 = 0.f;
        if (it == 0) {
            #pragma unroll
            for (int j = 0; j < JPT; ++j) {
                p0.x += u0[j].x; p0.y += u0[j].y; p0.z += u0[j].z; p0.w += u0[j].w;
                p1.x += u1[j].x; p1.y += u1[j].y; p1.z += u1[j].z; p1.w += u1[j].w;
            }
        } else {
            float m0 = bb0[0], m1 = bb1[0];
            #pragma unroll
            for (int j = 1; j < JPT; ++j) {
                m0 = fmaxf(m0, bb0[j]);
                m1 = fmaxf(m1, bb1[j]);
            }
            #pragma unroll
            for (int off = 1; off < 64; off <<= 1) {
                m0 = fmaxf(m0, __shfl_xor(m0, off));
                m1 = fmaxf(m1, __shfl_xor(m1, off));
            }
            if (lane == 0) { sbuf[0][wave] = m0; sbuf[1][wave] = m1; }
            __syncthreads();
            float M0 = sbuf[0][0], M1 = sbuf[1][0];
            #pragma unroll
            for (int wv = 1; wv < NWAVES; ++wv) {
                M0 = fmaxf(M0, sbuf[0][wv]);
                M1 = fmaxf(M1, sbuf[1][wv]);
            }
            // fused exp + weighted accumulate (no c[] array materialized)
            #pragma unroll
            for (int j = 0; j < JPT; ++j) {
                float e0 = __expf(bb0[j] - M0);
                float e1 = __expf(bb1[j] - M1);
                z0 += e0; z1 += e1;
                p0.x = fmaf(e0, u0[j].x, p0.x); p0.y = fmaf(e0, u0[j].y, p0.y);
                p0.z = fmaf(e0, u0[j].z, p0.z); p0.w = fmaf(e0, u0[j].w, p0.w);
                p1.x = fmaf(e1, u1[j].x, p1.x); p1.y = fmaf(e1, u1[j].y, p1.y);
                p1.z = fmaf(e1, u1[j].z, p1.z); p1.w = fmaf(e1, u1[j].w, p1.w);
            }
            z0 += __shfl_xor(z0, 1); z0 += __shfl_xor(z0, 2);
            z1 += __shfl_xor(z1, 1); z1 += __shfl_xor(z1, 2);
        }
        // reduce across the 16 row-groups (lane bits 2..5)
        #pragma unroll
        for (int off = 4; off < 64; off <<= 1) {
            p0.x += __shfl_xor(p0.x, off); p0.y += __shfl_xor(p0.y, off);
            p0.z += __shfl_xor(p0.z, off); p0.w += __shfl_xor(p0.w, off);
            p1.x += __shfl_xor(p1.x, off); p1.y += __shfl_xor(p1.y, off);
            p1.z += __shfl_xor(p1.z, off); p1.w += __shfl_xor(p1.w, off);
            if (it != 0) { z0 += __shfl_xor(z0, off); z1 += __shfl_xor(z1, off); }
        }
        if (nsub == 0) { red[0][wave][oq] = p0; red[1][wave][oq] = p1; }
        if (it != 0 && lane == 0) { zbuf[0][wave] = z0; zbuf[1][wave] = z1; }
        __syncthreads();

        if (t < 8) {   // bsel = t>>2, oq = t&3: combine, squash, publish
            const int bsel = t >> 2;
            const int o    = t & 3;
            float4 s = red[bsel][0][o];
            #pragma unroll
            for (int wv = 1; wv < NWAVES; ++wv) {
                float4 r = red[bsel][wv][o];
                s.x += r.x; s.y += r.y; s.z += r.z; s.w += r.w;
            }
            float scale;
            if (it == 0) {
                scale = 1.f / (float)NCAPS;
            } else {
                float Z = zbuf[bsel][0];
                #pragma unroll
                for (int wv = 1; wv < NWAVES; ++wv) Z += zbuf[bsel][wv];
                scale = 4.f / Z;   // each n replicated on 4 oq lanes
            }
            s.x *= scale; s.y *= scale; s.z *= scale; s.w *= scale;
            float4 v;
            v.x = s.x * fabsf(s.x) / (1.f + s.x * s.x);
            v.y = s.y * fabsf(s.y) / (1.f + s.y * s.y);
            v.z = s.z * fabsf(s.z) / (1.f + s.z * s.z);
            v.w = s.w * fabsf(s.w) / (1.f + s.w * s.w);
            vsh[bsel][o] = v;
            if (it == 2) {
                const int b = bsel ? b1 : b0;
                ((float4*)(out + ((size_t)d * BATCH + b) * COUT))[o] = v;
            }
        }
        __syncthreads();

        if (it < 2) {
            float4 v0 = vsh[0][oq];
            float4 v1 = vsh[1][oq];
            #pragma unroll
            for (int j = 0; j < JPT; ++j) {
                float dv0 = u0[j].x * v0.x + u0[j].y * v0.y +
                            u0[j].z * v0.z + u0[j].w * v0.w;
                float dv1 = u1[j].x * v1.x + u1[j].y * v1.y +
                            u1[j].z * v1.z + u1[j].w * v1.w;
                dv0 += __shfl_xor(dv0, 1); dv0 += __shfl_xor(dv0, 2);
                dv1 += __shfl_xor(dv1, 1); dv1 += __shfl_xor(dv1, 2);
                bb0[j] += dv0;
                bb1[j] += dv1;
            }
        }
    }
}

extern "C" void kernel_launch(void* const* d_in, const int* in_sizes, int n_in,
                              void* d_out, int out_size, void* d_ws, size_t ws_size,
                              hipStream_t stream) {
    const float* x = (const float*)d_in[0];
    const float* w = (const float*)d_in[1];
    float* out = (float*)d_out;
    digitcaps_kernel<<<DCAPS * BATCH / 2, NTHREADS, 0, stream>>>(x, w, out);
}

// Round 5
// 93.933 us; speedup vs baseline: 1.1500x; 1.1500x over previous
//
#include <hip/hip_runtime.h>
#include <hip/hip_bf16.h>
#include <math.h>

constexpr int NCAPS = 1152;
constexpr int CIN   = 8;
constexpr int COUT  = 16;
constexpr int BATCH = 128;
constexpr int DCAPS = 10;

// ---------------- Kernel A: u = einsum('bni,dnio->dbno'), bf16 out ----------
// Block = (d, 16-row n-chunk, 64-wide b-half). Thread = (oq, bgrp, nl): loads
// its w quad (8 x float4) ONCE and reuses it for 16 b's -> w traffic is read-
// once (11.8 MB total). Streaming, write-bound.
__global__ __launch_bounds__(256, 1) void u_kernel(
    const float* __restrict__ x,          // [128, 1152, 8]
    const float* __restrict__ w,          // [10, 1152, 8, 16]
    __hip_bfloat16* __restrict__ u)       // [10, 128, 1152, 16] bf16
{
    const int i  = blockIdx.x;
    const int bh = i & 1;                 // b-half
    const int nc = (i >> 1) % 72;         // n-chunk (16 rows)
    const int d  = (i >> 1) / 72;

    const int t    = threadIdx.x;
    const int oq   = t & 3;
    const int bgrp = (t >> 2) & 3;
    const int nl   = t >> 4;              // 0..15
    const int n    = nc * 16 + nl;
    const int b0   = bh * 64 + bgrp * 16;

    const float* wr = w + ((size_t)(d * NCAPS + n)) * (CIN * COUT) + oq * 4;
    float4 W[CIN];
    #pragma unroll
    for (int ii = 0; ii < CIN; ++ii)
        W[ii] = *(const float4*)(wr + ii * COUT);

    const float* xp = x + ((size_t)b0 * NCAPS + n) * CIN;
    __hip_bfloat16* up = u + ((size_t)(d * BATCH + b0) * NCAPS + n) * COUT + oq * 4;

    #pragma unroll
    for (int bi = 0; bi < 16; ++bi) {
        const float4* xr = (const float4*)(xp + (size_t)bi * NCAPS * CIN);
        float4 xa = xr[0], xc = xr[1];
        float xs[CIN] = {xa.x, xa.y, xa.z, xa.w, xc.x, xc.y, xc.z, xc.w};
        float4 acc = {0.f, 0.f, 0.f, 0.f};
        #pragma unroll
        for (int ii = 0; ii < CIN; ++ii) {
            acc.x = fmaf(xs[ii], W[ii].x, acc.x);
            acc.y = fmaf(xs[ii], W[ii].y, acc.y);
            acc.z = fmaf(xs[ii], W[ii].z, acc.z);
            acc.w = fmaf(xs[ii], W[ii].w, acc.w);
        }
        union { unsigned short us[4]; uint2 v; } pk;
        pk.us[0] = __bfloat16_as_ushort(__float2bfloat16(acc.x));
        pk.us[1] = __bfloat16_as_ushort(__float2bfloat16(acc.y));
        pk.us[2] = __bfloat16_as_ushort(__float2bfloat16(acc.z));
        pk.us[3] = __bfloat16_as_ushort(__float2bfloat16(acc.w));
        *(uint2*)(up + (size_t)bi * NCAPS * COUT) = pk.v;
    }
}

// ---------------- Kernel B: routing over precomputed u ----------------------
// Block = (d,b), 512 threads (8 waves). u slice (36.8 KB bf16) is read fully
// contiguously (512 B per wave-instr), expanded to f32 regs (9 float4/thr),
// then 3 routing iterations run in registers with xor-shuffle reductions.
constexpr int BNT    = 512;
constexpr int BWAVES = BNT / 64;
constexpr int QPT    = NCAPS * 4 / BNT;   // 9 o-quads per thread

__global__ __launch_bounds__(BNT, 1) void routing_kernel(
    const __hip_bfloat16* __restrict__ u, // [10, 128, 1152, 16] bf16
    float* __restrict__ out)              // [10, 128, 16]
{
    __shared__ float4 red[BWAVES][4];
    __shared__ float  sbuf[BWAVES];
    __shared__ float  zbuf[BWAVES];
    __shared__ float4 vsh[4];

    const int i = blockIdx.x;
    const int d = i >> 7;
    const int b = i & 127;

    const int t    = threadIdx.x;
    const int wave = t >> 6;
    const int lane = t & 63;
    const int oq   = t & 3;
    const int r    = t >> 2;              // 0..127

    const __hip_bfloat16* up =
        u + ((size_t)(d * BATCH + b) * NCAPS) * COUT + oq * 4;

    float4 u4[QPT];
    #pragma unroll
    for (int j = 0; j < QPT; ++j) {
        const int n = j * 128 + r;
        uint2 pv = *(const uint2*)(up + (size_t)n * COUT);
        float4 uf;
        uf.x = __uint_as_float(pv.x << 16);
        uf.y = __uint_as_float(pv.x & 0xffff0000u);
        uf.z = __uint_as_float(pv.y << 16);
        uf.w = __uint_as_float(pv.y & 0xffff0000u);
        u4[j] = uf;
    }

    float bb[QPT];
    #pragma unroll
    for (int j = 0; j < QPT; ++j) bb[j] = 0.f;

    #pragma unroll
    for (int it = 0; it < 3; ++it) {
        float4 p = {0.f, 0.f, 0.f, 0.f};
        float z = 0.f;
        if (it == 0) {
            #pragma unroll
            for (int j = 0; j < QPT; ++j) {
                p.x += u4[j].x; p.y += u4[j].y;
                p.z += u4[j].z; p.w += u4[j].w;
            }
        } else {
            float m = bb[0];
            #pragma unroll
            for (int j = 1; j < QPT; ++j) m = fmaxf(m, bb[j]);
            #pragma unroll
            for (int off = 1; off < 64; off <<= 1)
                m = fmaxf(m, __shfl_xor(m, off));
            if (lane == 0) sbuf[wave] = m;
            __syncthreads();
            float M = sbuf[0];
            #pragma unroll
            for (int wv = 1; wv < BWAVES; ++wv) M = fmaxf(M, sbuf[wv]);
            #pragma unroll
            for (int j = 0; j < QPT; ++j) {
                float e = __expf(bb[j] - M);
                z += e;
                p.x = fmaf(e, u4[j].x, p.x);
                p.y = fmaf(e, u4[j].y, p.y);
                p.z = fmaf(e, u4[j].z, p.z);
                p.w = fmaf(e, u4[j].w, p.w);
            }
            z += __shfl_xor(z, 1);
            z += __shfl_xor(z, 2);
        }
        #pragma unroll
        for (int off = 4; off < 64; off <<= 1) {
            p.x += __shfl_xor(p.x, off);
            p.y += __shfl_xor(p.y, off);
            p.z += __shfl_xor(p.z, off);
            p.w += __shfl_xor(p.w, off);
            if (it != 0) z += __shfl_xor(z, off);
        }
        if (lane < 4) red[wave][oq] = p;          // lanes 0..3: nsub==0
        if (it != 0 && lane == 0) zbuf[wave] = z;
        __syncthreads();

        if (t < 4) {   // t == oq: combine waves, squash, publish
            float4 s = red[0][t];
            #pragma unroll
            for (int wv = 1; wv < BWAVES; ++wv) {
                float4 rr = red[wv][t];
                s.x += rr.x; s.y += rr.y; s.z += rr.z; s.w += rr.w;
            }
            float scale;
            if (it == 0) {
                scale = 1.f / (float)NCAPS;
            } else {
                float Z = zbuf[0];
                #pragma unroll
                for (int wv = 1; wv < BWAVES; ++wv) Z += zbuf[wv];
                scale = 4.f / Z;   // each n replicated on 4 oq lanes
            }
            s.x *= scale; s.y *= scale; s.z *= scale; s.w *= scale;
            float4 v;
            v.x = s.x * fabsf(s.x) / (1.f + s.x * s.x);
            v.y = s.y * fabsf(s.y) / (1.f + s.y * s.y);
            v.z = s.z * fabsf(s.z) / (1.f + s.z * s.z);
            v.w = s.w * fabsf(s.w) / (1.f + s.w * s.w);
            vsh[t] = v;
            if (it == 2)
                ((float4*)(out + ((size_t)d * BATCH + b) * COUT))[t] = v;
        }
        __syncthreads();

        if (it < 2) {
            float4 v = vsh[oq];
            #pragma unroll
            for (int j = 0; j < QPT; ++j) {
                float dotv = u4[j].x * v.x + u4[j].y * v.y +
                             u4[j].z * v.z + u4[j].w * v.w;
                dotv += __shfl_xor(dotv, 1);
                dotv += __shfl_xor(dotv, 2);
                bb[j] += dotv;
            }
        }
    }
}

extern "C" void kernel_launch(void* const* d_in, const int* in_sizes, int n_in,
                              void* d_out, int out_size, void* d_ws, size_t ws_size,
                              hipStream_t stream) {
    const float* x = (const float*)d_in[0];
    const float* w = (const float*)d_in[1];
    float* out = (float*)d_out;
    __hip_bfloat16* u = (__hip_bfloat16*)d_ws;   // 10*128*1152*16*2 B = 47 MB

    u_kernel<<<DCAPS * 72 * 2, 256, 0, stream>>>(x, w, u);
    routing_kernel<<<DCAPS * BATCH, BNT, 0, stream>>>(u, out);
}